// Round 9
// baseline (302.432 us; speedup 1.0000x reference)
//
#include <hip/hip_runtime.h>

#define N_NODES 50000
#define N_EDGES 800000
#define F_E     128
#define HID     256
#define F_OUT   128
#define DIN     256          // F_X + F_E
#define LDA     264          // 256 + 8 bf16 pad (528B row stride -> <=2-way bank alias, free)
#define TILE_M  64           // nodes per tile
#define CAP     96           // slot capacity per node (Poisson(16); max deg ~45)
#define NB      ((N_NODES + TILE_M - 1) / TILE_M)   // 782 tiles
#define NPERSIST 512         // persistent blocks: 2 blocks/CU GUARANTEED resident
                             // (LDS 33.8KB*2=67.6<=160KB; launch_bounds(256,2) => VGPR<=256)

typedef __attribute__((ext_vector_type(8))) short short8;   // 8 bf16 = 4 VGPR (MFMA A/B frag)
typedef __attribute__((ext_vector_type(4))) float f32x4;    // MFMA C/D frag

__device__ __forceinline__ unsigned short f2bf(float f) {   // fp32 -> bf16 RNE
    unsigned int u = __float_as_uint(f);
    u = u + 0x7FFFu + ((u >> 16) & 1u);
    return (unsigned short)(u >> 16);
}

// ---------------------------------------------------------------------------
// ONE persistent kernel, 512 blocks (co-residency guaranteed by HW limits, not
// compiler luck — round-8 deadlock post-mortem). Pre-barrier: prestage tile0's
// x into LDS, W-prep slice, bucket-fill (2 sweeps x 1024 edges). Atomic grid
// barrier (agent scope, acq/rel for XCD coherence). Post-barrier: per owned
// tile, bucket gather-mean (16 nodes/wave, 2 rows/load-instr, 8 loads in
// flight) + bf16-MFMA MLP (layer1 64 hid cols/wave, layer2 32 out cols/wave).
// ---------------------------------------------------------------------------
__global__ __launch_bounds__(256, 2) void mono_kernel(const void* __restrict__ ei,
                                                      const float* __restrict__ x,
                                                      const float* __restrict__ edge_attr,
                                                      const float* __restrict__ W1,
                                                      const float* __restrict__ b1,
                                                      const float* __restrict__ W2,
                                                      const float* __restrict__ b2,
                                                      unsigned short* __restrict__ W1T,
                                                      unsigned short* __restrict__ W2T,
                                                      int* __restrict__ counts,
                                                      int* __restrict__ slots,
                                                      int* __restrict__ bar,
                                                      float* __restrict__ out) {
    __shared__ short A_lds[TILE_M * LDA];    // 33.8 KB: x|agg inputs, then h
    const int tid  = threadIdx.x;
    const int blk  = blockIdx.x;
    const int lane = tid & 63;
    const int wid  = tid >> 6;
    const int h    = lane >> 5;      // pair parity
    const int c    = lane & 31;      // feature quad: cols 4c..4c+3

    // ---- pre-barrier A: prestage tile0 (= blk) x rows into LDS
    {
        const int base = blk * TILE_M;
#pragma unroll
        for (int t = 0; t < 8; ++t) {
            const int nrow = wid * 16 + t * 2 + h;
            const int node = base + nrow;
            float4 xv = make_float4(0.f, 0.f, 0.f, 0.f);
            if (node < N_NODES) xv = *(const float4*)&x[node * 128 + 4 * c];
            *(ushort4*)&A_lds[nrow * LDA + 4 * c] =
                make_ushort4(f2bf(xv.x), f2bf(xv.y), f2bf(xv.z), f2bf(xv.w));
        }
    }

    // ---- pre-barrier B: W-prep slice (first 384 block-slices cover W1+W2)
    {
        const int idx = blk * 256 + tid;
        if (idx < DIN * HID) {
            const int j = idx & 255, k = idx >> 8;
            W1T[j * 256 + k] = f2bf(W1[k * 256 + j]);
        } else if (idx < DIN * HID + HID * F_OUT) {
            const int t2 = idx - DIN * HID;
            const int j = t2 & 127, k = t2 >> 7;
            W2T[j * 256 + k] = f2bf(W2[k * 128 + j]);
        }
    }

    // ---- pre-barrier C: bucket-fill, 2 sweeps of 1024 edges per block
    {
        const unsigned int* w = (const unsigned int*)ei;
        unsigned int oddacc = 0;
#pragma unroll
        for (int k = 0; k < 4; ++k) oddacc |= w[2 * (lane * 4 + k) + 1];
        const int is64 = (__ballot(oddacc != 0u) == 0ULL);

        for (int sweep = 0; sweep < 2; ++sweep) {
            const int e = (sweep * NPERSIST + blk) * 1024 + tid * 4;
            if (e < N_EDGES) {
                int d[4];
                if (is64) {
                    const long long* p = (const long long*)ei + N_EDGES + e;
                    longlong2 a = *(const longlong2*)p;
                    longlong2 b = *(const longlong2*)(p + 2);
                    d[0] = (int)a.x; d[1] = (int)a.y; d[2] = (int)b.x; d[3] = (int)b.y;
                } else {
                    int4 q = *(const int4*)((const int*)ei + N_EDGES + e);
                    d[0] = q.x; d[1] = q.y; d[2] = q.z; d[3] = q.w;
                }
#pragma unroll
                for (int j = 0; j < 4; ++j) {
                    int pos = atomicAdd(&counts[d[j]], 1);
                    if (pos < CAP) slots[d[j] * CAP + pos] = e + j;
                }
            }
        }
    }

    // ---- grid barrier (all NPERSIST blocks resident by construction)
    __syncthreads();
    if (tid == 0) {
        __hip_atomic_fetch_add(bar, 1, __ATOMIC_ACQ_REL, __HIP_MEMORY_SCOPE_AGENT);
        while (__hip_atomic_load(bar, __ATOMIC_ACQUIRE, __HIP_MEMORY_SCOPE_AGENT) < NPERSIST)
            __builtin_amdgcn_s_sleep(2);
    }
    __syncthreads();

    const int lr = lane & 15;
    const int lg = lane >> 4;
    const int wc  = wid * 64;
    const int wc2 = wid * 32;

    // ---- post-barrier: process owned tiles (blk, then blk+512 if it exists)
    for (int tile = blk; tile < NB; tile += NPERSIST) {
        const int base = tile * TILE_M;

        if (tile != blk) {
            __syncthreads();   // drain previous tile's LDS reads
#pragma unroll
            for (int t = 0; t < 8; ++t) {
                const int nrow = wid * 16 + t * 2 + h;
                const int node = base + nrow;
                float4 xv = make_float4(0.f, 0.f, 0.f, 0.f);
                if (node < N_NODES) xv = *(const float4*)&x[node * 128 + 4 * c];
                *(ushort4*)&A_lds[nrow * LDA + 4 * c] =
                    make_ushort4(f2bf(xv.x), f2bf(xv.y), f2bf(xv.z), f2bf(xv.w));
            }
        }

        // ---- gather-mean: 16 nodes per wave, 16 edges (8 loads) per iteration
        for (int nn = 0; nn < 16; ++nn) {
            const int nrow = wid * 16 + nn;
            const int node = base + nrow;
            int cnt = 0;
            if (node < N_NODES) {
                cnt = counts[node];
                cnt = cnt < CAP ? cnt : CAP;
            }
            const int beg = node * CAP;
            f32x4 acc = {0.f, 0.f, 0.f, 0.f};
            for (int p = 0; p < cnt; p += 16) {
                int eid[8];
#pragma unroll
                for (int j = 0; j < 8; ++j) {
                    int q = p + 2 * j + h;
                    q = q < cnt - 1 ? q : cnt - 1;        // clamp (re-read -> L1 hit)
                    eid[j] = slots[beg + q];
                }
                f32x4 v[8];
#pragma unroll
                for (int j = 0; j < 8; ++j)
                    v[j] = *(const f32x4*)&edge_attr[(size_t)eid[j] * F_E + 4 * c];
#pragma unroll
                for (int j = 0; j < 8; ++j)
                    if (p + 2 * j + h < cnt) acc += v[j];
            }
#pragma unroll
            for (int k = 0; k < 4; ++k) acc[k] += __shfl_xor(acc[k], 32);
            const float inv = 1.0f / (float)(cnt > 0 ? cnt : 1);
            if (h == 0)
                *(ushort4*)&A_lds[nrow * LDA + 128 + 4 * c] =
                    make_ushort4(f2bf(acc[0] * inv), f2bf(acc[1] * inv),
                                 f2bf(acc[2] * inv), f2bf(acc[3] * inv));
        }
        __syncthreads();

        // ---- layer 1: H[64][256] = relu(A @ W1 + b1), wave owns cols [wc, wc+64)
        f32x4 acc[4][4] = {};
#pragma unroll
        for (int kb = 0; kb < 8; ++kb) {
            short8 af[4];
#pragma unroll
            for (int m = 0; m < 4; ++m)
                af[m] = *(const short8*)&A_lds[(m * 16 + lr) * LDA + kb * 32 + lg * 8];
            short8 bf[4];
#pragma unroll
            for (int n = 0; n < 4; ++n)
                bf[n] = *(const short8*)&W1T[(wc + n * 16 + lr) * 256 + kb * 32 + lg * 8];
#pragma unroll
            for (int m = 0; m < 4; ++m)
#pragma unroll
                for (int n = 0; n < 4; ++n)
                    acc[m][n] = __builtin_amdgcn_mfma_f32_16x16x32_bf16(af[m], bf[n], acc[m][n], 0, 0, 0);
        }

        float b1v[4];
#pragma unroll
        for (int n = 0; n < 4; ++n) b1v[n] = b1[wc + n * 16 + lr];

        __syncthreads();   // all waves done reading A; reuse buffer for H
#pragma unroll
        for (int m = 0; m < 4; ++m)
#pragma unroll
            for (int n = 0; n < 4; ++n)
#pragma unroll
                for (int i = 0; i < 4; ++i) {
                    float hh = acc[m][n][i] + b1v[n];
                    hh = hh > 0.f ? hh : 0.f;
                    A_lds[(m * 16 + lg * 4 + i) * LDA + wc + n * 16 + lr] = (short)f2bf(hh);
                }
        __syncthreads();

        // ---- layer 2: out = H @ W2 + b2, wave owns cols [wc2, wc2+32)
        f32x4 acc2[4][2] = {};
#pragma unroll
        for (int kb = 0; kb < 8; ++kb) {
            short8 af[4];
#pragma unroll
            for (int m = 0; m < 4; ++m)
                af[m] = *(const short8*)&A_lds[(m * 16 + lr) * LDA + kb * 32 + lg * 8];
            short8 bf[2];
#pragma unroll
            for (int n = 0; n < 2; ++n)
                bf[n] = *(const short8*)&W2T[(wc2 + n * 16 + lr) * 256 + kb * 32 + lg * 8];
#pragma unroll
            for (int m = 0; m < 4; ++m)
#pragma unroll
                for (int n = 0; n < 2; ++n)
                    acc2[m][n] = __builtin_amdgcn_mfma_f32_16x16x32_bf16(af[m], bf[n], acc2[m][n], 0, 0, 0);
        }

        float b2v[2];
#pragma unroll
        for (int n = 0; n < 2; ++n) b2v[n] = b2[wc2 + n * 16 + lr];
#pragma unroll
        for (int m = 0; m < 4; ++m)
#pragma unroll
            for (int n = 0; n < 2; ++n)
#pragma unroll
                for (int i = 0; i < 4; ++i) {
                    int node = base + m * 16 + lg * 4 + i;
                    if (node < N_NODES)
                        out[node * F_OUT + wc2 + n * 16 + lr] = acc2[m][n][i] + b2v[n];
                }
    }
}

// ---------------------------------------------------------------------------
extern "C" void kernel_launch(void* const* d_in, const int* in_sizes, int n_in,
                              void* d_out, int out_size, void* d_ws, size_t ws_size,
                              hipStream_t stream) {
    const float* x         = (const float*)d_in[0];
    const void*  ei        = d_in[1];
    const float* edge_attr = (const float*)d_in[2];
    const float* W1        = (const float*)d_in[3];
    const float* b1        = (const float*)d_in[4];
    const float* W2        = (const float*)d_in[5];
    const float* b2        = (const float*)d_in[6];
    float* out = (float*)d_out;

    char* ws = (char*)d_ws;
    size_t off = 0;
    auto alloc = [&](size_t bytes) -> void* {
        void* p = ws + off;
        off = (off + bytes + 255) & ~(size_t)255;
        return p;
    };
    int*            counts = (int*)alloc((size_t)N_NODES * 4);            // 200 KB
    int*            bar    = (int*)alloc(256);                            // barrier counter
    int*            slots  = (int*)alloc((size_t)N_NODES * CAP * 4);      // 19.2 MB
    unsigned short* w1t    = (unsigned short*)alloc((size_t)DIN * HID * 2);
    unsigned short* w2t    = (unsigned short*)alloc((size_t)HID * F_OUT * 2);
    (void)ws_size; (void)in_sizes; (void)n_in; (void)out_size;

    // zero counts + barrier counter (contiguous at ws start)
    hipMemsetAsync(ws, 0, (size_t)((char*)bar - ws) + 256, stream);
    mono_kernel<<<NPERSIST, 256, 0, stream>>>(ei, x, edge_attr, W1, b1, W2, b2,
                                              w1t, w2t, counts, slots, bar, out);
}

// Round 10
// 196.403 us; speedup vs baseline: 1.5399x; 1.5399x over previous
//
#include <hip/hip_runtime.h>

#define N_NODES 50000
#define N_EDGES 800000
#define F_E     128
#define HID     256
#define F_OUT   128
#define DIN     256          // F_X + F_E
#define LDA     264          // 256 + 8 bf16 pad (528B row stride -> <=2-way bank alias, free)
#define TILE_M  32           // nodes per block
#define CAP     96           // slot capacity per node (Poisson(16); max deg ~45)
#define PREP_BLOCKS ((DIN * HID + HID * F_OUT) / 256)          // 384

typedef __attribute__((ext_vector_type(8))) short short8;   // 8 bf16 = 4 VGPR (MFMA A/B frag)
typedef __attribute__((ext_vector_type(4))) float f32x4;    // MFMA C/D frag

__device__ __forceinline__ unsigned short f2bf(float f) {   // fp32 -> bf16 RNE
    unsigned int u = __float_as_uint(f);
    u = u + 0x7FFFu + ((u >> 16) & 1u);
    return (unsigned short)(u >> 16);
}

// ---------------------------------------------------------------------------
// COMBO kernel: blocks [0, PREP_BLOCKS) convert W1/W2 -> bf16 transposed;
// remaining blocks bucket-fill: pos = atomicAdd(count[dst]), slots[dst*CAP+pos]=e.
// edge_index dtype (int64 vs int32) detected per-wave via ballot over odd words.
// ---------------------------------------------------------------------------
__global__ __launch_bounds__(256) void combo_kernel(const void* ei,
                                                    const float* __restrict__ W1,
                                                    const float* __restrict__ W2,
                                                    unsigned short* __restrict__ W1T,
                                                    unsigned short* __restrict__ W2T,
                                                    int* __restrict__ counts,
                                                    int* __restrict__ slots) {
    const int tid = threadIdx.x;
    if (blockIdx.x < PREP_BLOCKS) {
        int idx = blockIdx.x * 256 + tid;
        if (idx < DIN * HID) {
            int j = idx & 255, k = idx >> 8;
            W1T[j * 256 + k] = f2bf(W1[k * 256 + j]);
        } else {
            int t = idx - DIN * HID;            // 0..32767
            int j = t & 127, k = t >> 7;
            W2T[j * 256 + k] = f2bf(W2[k * 128 + j]);
        }
        return;
    }
    // ---- fill portion, self-detecting dtype
    const int lane = tid & 63;
    const unsigned int* w = (const unsigned int*)ei;
    unsigned int oddacc = 0;
#pragma unroll
    for (int k = 0; k < 4; ++k) oddacc |= w[2 * (lane * 4 + k) + 1];
    const int is64 = (__ballot(oddacc != 0u) == 0ULL);

    const int e = ((int)blockIdx.x - PREP_BLOCKS) * 1024 + tid * 4;
    if (e >= N_EDGES) return;
    int d[4];
    if (is64) {
        const long long* p = (const long long*)ei + N_EDGES + e;
        longlong2 a = *(const longlong2*)p;
        longlong2 b = *(const longlong2*)(p + 2);
        d[0] = (int)a.x; d[1] = (int)a.y; d[2] = (int)b.x; d[3] = (int)b.y;
    } else {
        int4 q = *(const int4*)((const int*)ei + N_EDGES + e);
        d[0] = q.x; d[1] = q.y; d[2] = q.z; d[3] = q.w;
    }
#pragma unroll
    for (int j = 0; j < 4; ++j) {
        int pos = atomicAdd(&counts[d[j]], 1);
        if (pos < CAP) slots[d[j] * CAP + pos] = e + j;
    }
}

// ---------------------------------------------------------------------------
// FUSED: bucket gather-mean + bf16-MFMA MLP. 256 thr = 4 waves, 32 nodes/block.
// NEW vs r7: block's slot slice (contiguous 12.3KB) + counts staged into LDS
// with coalesced int4 loads -> gather's eid reads have ~zero latency, removing
// the dependent global slot-load in front of every 8-row burst.
// Gather: wave owns 8 nodes; lane=(h=lane>>5, c=lane&31); each half-wave reads
//   a DIFFERENT edge row as float4 (2 edges/instr), 8 loads in flight.
// MLP: layer1 wave owns 64 hid cols (acc[2][4]); layer2 32 out cols (acc2[2][2]).
// ---------------------------------------------------------------------------
__global__ __launch_bounds__(256) void fused_mlp_kernel(const float* __restrict__ x,
                                                        const float* __restrict__ edge_attr,
                                                        const int* __restrict__ counts,
                                                        const int* __restrict__ slots,
                                                        const unsigned short* __restrict__ W1T,
                                                        const float* __restrict__ b1,
                                                        const unsigned short* __restrict__ W2T,
                                                        const float* __restrict__ b2,
                                                        float* __restrict__ out) {
    __shared__ short A_lds[TILE_M * LDA];    // 16.9 KB, inputs then h
    __shared__ int   S_lds[TILE_M * CAP];    // 12.3 KB, block's slot slice
    __shared__ int   C_lds[TILE_M];
    const int tid  = threadIdx.x;
    const int base = blockIdx.x * TILE_M;
    const int lane = tid & 63;
    const int wid  = tid >> 6;
    const int h    = lane >> 5;      // edge parity within a pair
    const int c    = lane & 31;      // feature quad: cols 4c..4c+3

    // ---- phase 0: stage slot slice + counts into LDS (coalesced, 3 int4/thread)
    {
        const int4* sg = (const int4*)&slots[(size_t)base * CAP];
        int4* sl = (int4*)S_lds;
#pragma unroll
        for (int i = 0; i < (TILE_M * CAP / 4) / 256; ++i)
            sl[tid + 256 * i] = sg[tid + 256 * i];
        if (tid < TILE_M)
            C_lds[tid] = (base + tid < N_NODES) ? counts[base + tid] : 0;
    }

    // ---- phase 1a: stage x rows (2 rows per instruction, fully coalesced 1KB)
#pragma unroll
    for (int t = 0; t < 4; ++t) {
        const int nrow = wid * 8 + t * 2 + h;
        const int node = base + nrow;
        float4 xv = make_float4(0.f, 0.f, 0.f, 0.f);
        if (node < N_NODES) xv = *(const float4*)&x[node * 128 + 4 * c];
        *(ushort4*)&A_lds[nrow * LDA + 4 * c] =
            make_ushort4(f2bf(xv.x), f2bf(xv.y), f2bf(xv.z), f2bf(xv.w));
    }
    __syncthreads();   // S_lds/C_lds visible to all waves

    // ---- phase 1b: bucket gather-mean, 8 nodes per wave, 16 edges per iter
    for (int nn = 0; nn < 8; ++nn) {
        const int nrow = wid * 8 + nn;
        int cnt = C_lds[nrow];
        cnt = cnt < CAP ? cnt : CAP;
        f32x4 acc = {0.f, 0.f, 0.f, 0.f};
        for (int p = 0; p < cnt; p += 16) {
            int eid[8];
#pragma unroll
            for (int j = 0; j < 8; ++j) {
                int q = p + 2 * j + h;
                q = q < cnt - 1 ? q : cnt - 1;        // clamp
                eid[j] = S_lds[nrow * CAP + q];
            }
            f32x4 v[8];
#pragma unroll
            for (int j = 0; j < 8; ++j)
                v[j] = *(const f32x4*)&edge_attr[(size_t)eid[j] * F_E + 4 * c];
#pragma unroll
            for (int j = 0; j < 8; ++j)
                if (p + 2 * j + h < cnt) acc += v[j];
        }
        // merge the two parity partial sums
#pragma unroll
        for (int k = 0; k < 4; ++k) acc[k] += __shfl_xor(acc[k], 32);
        const float inv = 1.0f / (float)(cnt > 0 ? cnt : 1);
        if (h == 0)
            *(ushort4*)&A_lds[nrow * LDA + 128 + 4 * c] =
                make_ushort4(f2bf(acc[0] * inv), f2bf(acc[1] * inv),
                             f2bf(acc[2] * inv), f2bf(acc[3] * inv));
    }
    __syncthreads();

    const int lr = lane & 15;
    const int lg = lane >> 4;
    const int wc = wid * 64;

    // ---- phase 2: H[32][256] = relu(A @ W1 + b1), wave owns cols [wc, wc+64)
    f32x4 acc[2][4] = {};
#pragma unroll
    for (int kb = 0; kb < 8; ++kb) {
        short8 af[2];
#pragma unroll
        for (int m = 0; m < 2; ++m)
            af[m] = *(const short8*)&A_lds[(m * 16 + lr) * LDA + kb * 32 + lg * 8];
        short8 bf[4];
#pragma unroll
        for (int n = 0; n < 4; ++n)
            bf[n] = *(const short8*)&W1T[(wc + n * 16 + lr) * 256 + kb * 32 + lg * 8];
#pragma unroll
        for (int m = 0; m < 2; ++m)
#pragma unroll
            for (int n = 0; n < 4; ++n)
                acc[m][n] = __builtin_amdgcn_mfma_f32_16x16x32_bf16(af[m], bf[n], acc[m][n], 0, 0, 0);
    }

    float b1v[4];
#pragma unroll
    for (int n = 0; n < 4; ++n) b1v[n] = b1[wc + n * 16 + lr];

    __syncthreads();   // all waves done reading A; reuse buffer for H
#pragma unroll
    for (int m = 0; m < 2; ++m)
#pragma unroll
        for (int n = 0; n < 4; ++n)
#pragma unroll
            for (int i = 0; i < 4; ++i) {
                float hh = acc[m][n][i] + b1v[n];
                hh = hh > 0.f ? hh : 0.f;
                A_lds[(m * 16 + lg * 4 + i) * LDA + wc + n * 16 + lr] = (short)f2bf(hh);
            }
    __syncthreads();

    // ---- phase 3: out = H @ W2 + b2, wave owns cols [wid*32, wid*32+32)
    const int wc2 = wid * 32;
    f32x4 acc2[2][2] = {};
#pragma unroll
    for (int kb = 0; kb < 8; ++kb) {
        short8 af[2];
#pragma unroll
        for (int m = 0; m < 2; ++m)
            af[m] = *(const short8*)&A_lds[(m * 16 + lr) * LDA + kb * 32 + lg * 8];
        short8 bf[2];
#pragma unroll
        for (int n = 0; n < 2; ++n)
            bf[n] = *(const short8*)&W2T[(wc2 + n * 16 + lr) * 256 + kb * 32 + lg * 8];
#pragma unroll
        for (int m = 0; m < 2; ++m)
#pragma unroll
            for (int n = 0; n < 2; ++n)
                acc2[m][n] = __builtin_amdgcn_mfma_f32_16x16x32_bf16(af[m], bf[n], acc2[m][n], 0, 0, 0);
    }

    float b2v[2];
#pragma unroll
    for (int n = 0; n < 2; ++n) b2v[n] = b2[wc2 + n * 16 + lr];
#pragma unroll
    for (int m = 0; m < 2; ++m)
#pragma unroll
        for (int n = 0; n < 2; ++n)
#pragma unroll
            for (int i = 0; i < 4; ++i) {
                int node = base + m * 16 + lg * 4 + i;
                if (node < N_NODES)
                    out[node * F_OUT + wc2 + n * 16 + lr] = acc2[m][n][i] + b2v[n];
            }
}

// ---------------------------------------------------------------------------
extern "C" void kernel_launch(void* const* d_in, const int* in_sizes, int n_in,
                              void* d_out, int out_size, void* d_ws, size_t ws_size,
                              hipStream_t stream) {
    const float* x         = (const float*)d_in[0];
    const void*  ei        = d_in[1];
    const float* edge_attr = (const float*)d_in[2];
    const float* W1        = (const float*)d_in[3];
    const float* b1        = (const float*)d_in[4];
    const float* W2        = (const float*)d_in[5];
    const float* b2        = (const float*)d_in[6];
    float* out = (float*)d_out;

    char* ws = (char*)d_ws;
    size_t off = 0;
    auto alloc = [&](size_t bytes) -> void* {
        void* p = ws + off;
        off = (off + bytes + 255) & ~(size_t)255;
        return p;
    };
    int*            counts = (int*)alloc((size_t)N_NODES * 4);
    // +TILE_M rows of padding: last block stages a full TILE_M*CAP slice
    int*            slots  = (int*)alloc((size_t)(N_NODES + TILE_M) * CAP * 4);   // 19.2 MB
    unsigned short* w1t    = (unsigned short*)alloc((size_t)DIN * HID * 2);
    unsigned short* w2t    = (unsigned short*)alloc((size_t)HID * F_OUT * 2);
    (void)ws_size; (void)in_sizes; (void)n_in; (void)out_size;

    hipMemsetAsync(counts, 0, (size_t)N_NODES * 4, stream);
    const int fill_blocks = (N_EDGES / 4 + 255) / 256;   // 782
    combo_kernel<<<PREP_BLOCKS + fill_blocks, 256, 0, stream>>>(ei, W1, W2, w1t, w2t,
                                                                counts, slots);
    fused_mlp_kernel<<<(N_NODES + TILE_M - 1) / TILE_M, 256, 0, stream>>>(
        x, edge_attr, counts, slots, w1t, b1, w2t, b2, out);
}